// Round 15
// baseline (41974.777 us; speedup 1.0000x reference)
//
#include <hip/hip_runtime.h>
#include <math.h>

#define BB 256   // batch
#define TT 512   // encoder seq len
#define DD 64    // state dim
#define HH 512   // hidden dim
#define FF 32    // fc_seq_len (decoder steps)

__device__ __forceinline__ float sigmoidf_(float x) { return 1.0f / (1.0f + __expf(-x)); }

// ---------------- per-step GRU kernel, weight-slice stationary in LDS ----------------
// grid (64, 4): jt = blockIdx.x (8 j-cols), g = blockIdx.y (64 batch rows).
// 128 threads (2 waves): jj = tid>>4 (0..7), bi = tid&15; n=4 rows per thread.
// Identical to round 14 EXCEPT the W-slice load is vectorized float4,
// pipelined 9-deep (round 14 used a scalar loop -> suspected regression cause;
// this round is the single-variable test).
#define THRG 128
struct SmemW {
    float w[3][8][580];    // stride 580: 16B rows, banks 4jj+k -> spread
    float hbuf[64][36];    // stride 36: 16B rows
};                         // 55680 + 9216 = 64896 B <= 64 KiB

// stage 64 rows x 32 cols of src (row stride rs): 4 float4/thread.
__device__ __forceinline__ void stage_issue(float4* pre, const float* __restrict__ src,
                                            int rs, int kc, int b0, int tid) {
    #pragma unroll
    for (int u = 0; u < 4; ++u) {
        const int idx = u * THRG + tid, r = idx >> 3, c4 = idx & 7;
        pre[u] = *(const float4*)&src[(b0 + r) * rs + kc + c4 * 4];
    }
}
__device__ __forceinline__ void stage_commit(float (*buf)[36], const float4* pre, int tid) {
    #pragma unroll
    for (int u = 0; u < 4; ++u) {
        const int idx = u * THRG + tid, r = idx >> 3, c4 = idx & 7;
        *(float4*)&buf[r][c4 * 4] = pre[u];
    }
}

// one 32-K chunk of the 3 gate GEMMs, n=4 rows
__device__ __forceinline__ void gru_chunk(const SmemW& g, int jj, int bi, int kb,
                                          float* ar, float* az, float* an) {
    #pragma unroll
    for (int kk = 0; kk < 32; kk += 2) {
        const float2 w0 = *(const float2*)&g.w[0][jj][kb + kk];
        const float2 w1 = *(const float2*)&g.w[1][jj][kb + kk];
        const float2 w2 = *(const float2*)&g.w[2][jj][kb + kk];
        #pragma unroll
        for (int q = 0; q < 4; ++q) {
            const float2 hv = *(const float2*)&g.hbuf[bi + 16 * q][kk];
            ar[q] = fmaf(hv.x, w0.x, ar[q]); ar[q] = fmaf(hv.y, w0.y, ar[q]);
            az[q] = fmaf(hv.x, w1.x, az[q]); az[q] = fmaf(hv.y, w1.y, az[q]);
            an[q] = fmaf(hv.x, w2.x, an[q]); an[q] = fmaf(hv.y, w2.y, an[q]);
        }
    }
}

__global__ __launch_bounds__(THRG) void gru_step_w(
    const float* __restrict__ x, int xs,             // [BB, *] rows at stride xs
    const float* __restrict__ h,                     // [BB, HH] or nullptr (zeros)
    const float* __restrict__ W_ih, const float* __restrict__ W_hh,
    const float* __restrict__ b_ih, const float* __restrict__ b_hh,
    float* __restrict__ hnew,                        // [BB, HH]
    float* __restrict__ h2, int h2s)                 // optional extra write (h_seq)
{
    __shared__ SmemW sm;
    const int tid = threadIdx.x;
    const int j0 = blockIdx.x * 8, b0 = blockIdx.y * 64;
    const int jj = tid >> 4, bi = tid & 15;
    const int j = j0 + jj;

    // ---- W slice -> LDS: 3456 float4s (27/thread), pipelined 9-deep.
    // i4 -> gg = i4/1152, r = (i4%1152)/144, k4 = i4%144; k4<16 = W_ih.
    #pragma unroll
    for (int half = 0; half < 3; ++half) {
        float4 tmp[9];
        #pragma unroll
        for (int u = 0; u < 9; ++u) {
            const int i4 = (half * 9 + u) * THRG + tid;      // < 3456 always
            const int gg = i4 / 1152, rem = i4 - gg * 1152;
            const int r = rem / 144, k4 = rem - r * 144;
            const float* src = (k4 < 16)
                ? &W_ih[(gg * HH + j0 + r) * DD + k4 * 4]
                : &W_hh[(gg * HH + j0 + r) * HH + (k4 - 16) * 4];
            tmp[u] = *(const float4*)src;
        }
        #pragma unroll
        for (int u = 0; u < 9; ++u) {
            const int i4 = (half * 9 + u) * THRG + tid;
            const int gg = i4 / 1152, rem = i4 - gg * 1152;
            const int r = rem / 144, k4 = rem - r * 144;
            *(float4*)&sm.w[gg][r][k4 * 4] = tmp[u];
        }
    }
    const float br  = b_ih[j] + b_hh[j];
    const float bz  = b_ih[HH + j] + b_hh[HH + j];
    const float bin = b_ih[2 * HH + j];
    const float bhn = b_hh[2 * HH + j];

    float ar[4] = {0,0,0,0}, az[4] = {0,0,0,0}, ain[4] = {0,0,0,0}, ahn[4] = {0,0,0,0};
    float4 pre[4];

    // ---- x part: K 0..63 (weight cols 0..63) ----
    stage_issue(pre, x, xs, 0, b0, tid);
    stage_commit(sm.hbuf, pre, tid);
    __syncthreads();                                  // covers W load + chunk 0
    stage_issue(pre, x, xs, 32, b0, tid);
    gru_chunk(sm, jj, bi, 0, ar, az, ain);
    __syncthreads();
    stage_commit(sm.hbuf, pre, tid);
    __syncthreads();
    gru_chunk(sm, jj, bi, 32, ar, az, ain);
    __syncthreads();

    // ---- h part: K 0..511 (weight cols 64..575) ----
    if (h) {
        stage_issue(pre, h, HH, 0, b0, tid);
        stage_commit(sm.hbuf, pre, tid);
        __syncthreads();
        for (int c = 0; c < 16; ++c) {
            if (c < 15) stage_issue(pre, h, HH, 32 * (c + 1), b0, tid);
            gru_chunk(sm, jj, bi, 64 + 32 * c, ar, az, ahn);
            __syncthreads();
            if (c < 15) { stage_commit(sm.hbuf, pre, tid); __syncthreads(); }
        }
    }

    // ---- epilogue: n = tanh(i_n + r*h_n); h' = (1-z)n + z h ----
    #pragma unroll
    for (int q = 0; q < 4; ++q) {
        const int b = b0 + bi + 16 * q;
        const float r = sigmoidf_(ar[q] + br);
        const float z = sigmoidf_(az[q] + bz);
        const float hold = h ? h[b * HH + j] : 0.f;
        const float n = tanhf(ain[q] + bin + r * (ahn[q] + bhn));
        const float hn = (1.f - z) * n + z * hold;
        hnew[b * HH + j] = hn;
        if (h2) h2[b * h2s + j] = hn;
    }
}

// ---------------- fc kernels (round-3/9-verified) ----------------
struct SmemOld { float hs[16][34]; float ws[96][34]; };

__global__ __launch_bounds__(256) void fc1_relu(
    const float* __restrict__ h, const float* __restrict__ wsrc,
    const float* __restrict__ bias, float* __restrict__ out) {
    __shared__ SmemOld sm;
    float (*hs)[34] = sm.hs; float (*ws)[34] = sm.ws;
    const int tid = threadIdx.x;
    const int jj = tid & 31, bb = tid >> 5;
    const int j0 = blockIdx.x * 32, b0 = blockIdx.y * 16;
    float a0 = 0.f, a1 = 0.f;
    for (int kt = 0; kt < HH; kt += 32) {
        { const int r = tid >> 4, c2 = (tid & 15) * 2;
          *(float2*)&hs[r][c2] = *(const float2*)&h[(b0 + r) * HH + kt + c2]; }
        #pragma unroll
        for (int i = 0; i < 2; ++i) {
            const int idx = i * 256 + tid, r = idx >> 4, c2 = (idx & 15) * 2;
            *(float2*)&ws[r][c2] = *(const float2*)&wsrc[(j0 + r) * HH + kt + c2];
        }
        __syncthreads();
        #pragma unroll
        for (int k = 0; k < 32; k += 2) {
            const float2 h0 = *(const float2*)&hs[bb][k];
            const float2 h1 = *(const float2*)&hs[bb + 8][k];
            const float2 w0 = *(const float2*)&ws[jj][k];
            a0 = fmaf(h0.x, w0.x, a0); a0 = fmaf(h0.y, w0.y, a0);
            a1 = fmaf(h1.x, w0.x, a1); a1 = fmaf(h1.y, w0.y, a1);
        }
        __syncthreads();
    }
    const float b = bias[j0 + jj];
    out[(b0 + bb) * HH + j0 + jj]     = fmaxf(a0 + b, 0.f);
    out[(b0 + bb + 8) * HH + j0 + jj] = fmaxf(a1 + b, 0.f);
}

__global__ __launch_bounds__(256) void fc2_out(
    const float* __restrict__ a, const float* __restrict__ wsrc,
    const float* __restrict__ bias, float* __restrict__ s_buf,
    float* __restrict__ s_out, int s_stride) {
    __shared__ SmemOld sm;
    float (*as)[34] = sm.hs; float (*ws)[34] = sm.ws;
    const int tid = threadIdx.x;
    const int d = tid & 63, bb = tid >> 6;
    const int b0 = blockIdx.x * 4;
    float acc = 0.f;
    for (int kt = 0; kt < HH; kt += 32) {
        if (tid < 64) { const int r = tid >> 4, c2 = (tid & 15) * 2;
            *(float2*)&as[r][c2] = *(const float2*)&a[(b0 + r) * HH + kt + c2]; }
        #pragma unroll
        for (int i = 0; i < 4; ++i) {
            const int idx = i * 256 + tid, r = idx >> 4, c2 = (idx & 15) * 2;
            *(float2*)&ws[r][c2] = *(const float2*)&wsrc[r * HH + kt + c2];
        }
        __syncthreads();
        #pragma unroll
        for (int k = 0; k < 32; k += 2) {
            const float2 av = *(const float2*)&as[bb][k];
            const float2 wv = *(const float2*)&ws[d][k];
            acc = fmaf(av.x, wv.x, acc); acc = fmaf(av.y, wv.y, acc);
        }
        __syncthreads();
    }
    const float v = acc + bias[d];
    s_buf[(b0 + bb) * DD + d] = v;
    s_out[(b0 + bb) * s_stride + d] = v;
}

extern "C" void kernel_launch(void* const* d_in, const int* in_sizes, int n_in,
                              void* d_out, int out_size, void* d_ws, size_t ws_size,
                              hipStream_t stream) {
    const float* state_seq = (const float*)d_in[0];  // [256,512,64]
    const float* W_ih  = (const float*)d_in[1];      // [1536,64]
    const float* W_hh  = (const float*)d_in[2];      // [1536,512]
    const float* b_ih  = (const float*)d_in[3];
    const float* b_hh  = (const float*)d_in[4];
    const float* fc1_w = (const float*)d_in[5];      // [512,512]
    const float* fc1_b = (const float*)d_in[6];
    const float* fc2_w = (const float*)d_in[7];      // [64,512]
    const float* fc2_b = (const float*)d_in[8];

    float* out_s = (float*)d_out;                    // [256, 32, 64]
    float* out_h = out_s + BB * FF * DD;             // [256, 32, 512]

    float* hA   = (float*)d_ws;
    float* hB   = hA + BB * HH;
    float* aBuf = hB + BB * HH;
    float* sBuf = aBuf + BB * HH;

    const dim3 gruGrid(HH / 8, BB / 64);             // (64, 4)
    const dim3 gruBlk(THRG);

    // ---- encoder: 512 per-step launches (launch boundary = h sync) ----
    const float* hcur = nullptr;
    for (int t = 0; t < TT; ++t) {
        float* hout = (t & 1) ? hB : hA;
        float* hout2 = (t == TT - 1) ? out_h : nullptr;   // h_seq[:,0,:]
        gru_step_w<<<gruGrid, gruBlk, 0, stream>>>(state_seq + t * DD, TT * DD, hcur,
                                                   W_ih, W_hh, b_ih, b_hh,
                                                   hout, hout2, FF * HH);
        hcur = hout;
    }

    // ---- decoder: 32 fc_predicts, 31 GRU steps ----
    for (int t = 0; t < FF; ++t) {
        fc1_relu<<<dim3(HH / 32, BB / 16), dim3(256), 0, stream>>>(hcur, fc1_w, fc1_b, aBuf);
        fc2_out<<<dim3(BB / 4), dim3(256), 0, stream>>>(aBuf, fc2_w, fc2_b, sBuf,
                                                        out_s + t * DD, FF * DD);
        if (t < FF - 1) {
            float* hout = (hcur == hA) ? hB : hA;
            gru_step_w<<<gruGrid, gruBlk, 0, stream>>>(sBuf, DD, hcur,
                                                       W_ih, W_hh, b_ih, b_hh,
                                                       hout, out_h + (t + 1) * HH, FF * HH);
            hcur = hout;
        }
    }
}

// Round 16
// 16851.593 us; speedup vs baseline: 2.4908x; 2.4908x over previous
//
#include <hip/hip_runtime.h>
#include <math.h>

#define BB 256   // batch
#define TT 512   // encoder seq len
#define DD 64    // state dim
#define HH 512   // hidden dim
#define FF 32    // fc_seq_len (decoder steps)
#define THRG 128 // threads per wg (2 waves); 2 wgs/CU via 36.5 KB LDS

__device__ __forceinline__ float sigmoidf_(float x) { return 1.0f / (1.0f + __expf(-x)); }

// ---------------- per-step GRU kernel, 2 wgs/CU, r9 body shape ----------------
// grid (128, 4): jt = blockIdx.x (4 j-cols), g = blockIdx.y (64 batch rows).
// 128 threads: jj = tid>>5 (0..3), bi = tid&31, q in {0,1}: rows b0+bi, +32.
// Per-thread shape identical to round 9 (verified 17.36 ms); j-slice halved so
// TWO wgs fit per CU -> independent wgs overlap barrier/stage stalls (r14/r15
// showed 1 wg x 2 waves is latency-bound; r9 was 1 wg x 4 lockstep waves).
struct __align__(16) SmemW {
    float w[3][4][580];    // 27840 B; stride 580 (16B rows), banks 4jj+k
    float hbuf[64][34];    // 8704 B; stride 34: 2-way alias on reads (free)
};                         // 36544 B -> 2 blocks/CU

// stage 64 rows x 32 cols of src (row stride rs): 8 float2/thread (r9 pattern).
__device__ __forceinline__ void stage_issue(float2* pre, const float* __restrict__ src,
                                            int rs, int kc, int b0, int tid) {
    #pragma unroll
    for (int u = 0; u < 8; ++u) {
        const int idx = u * THRG + tid, r = idx >> 4, c2 = (idx & 15) * 2;
        pre[u] = *(const float2*)&src[(b0 + r) * rs + kc + c2];
    }
}
__device__ __forceinline__ void stage_commit(float (*buf)[34], const float2* pre, int tid) {
    #pragma unroll
    for (int u = 0; u < 8; ++u) {
        const int idx = u * THRG + tid, r = idx >> 4, c2 = (idx & 15) * 2;
        *(float2*)&buf[r][c2] = pre[u];
    }
}

// one 32-K chunk of the 3 gate GEMMs (r9's gru_chunk, jj range 0..3)
__device__ __forceinline__ void gru_chunk(const SmemW& g, int jj, int bi, int kb,
                                          float* ar, float* az, float* an) {
    #pragma unroll
    for (int kk = 0; kk < 32; kk += 2) {
        const float2 w0 = *(const float2*)&g.w[0][jj][kb + kk];
        const float2 w1 = *(const float2*)&g.w[1][jj][kb + kk];
        const float2 w2 = *(const float2*)&g.w[2][jj][kb + kk];
        #pragma unroll
        for (int q = 0; q < 2; ++q) {
            const float2 hv = *(const float2*)&g.hbuf[bi + 32 * q][kk];
            ar[q] = fmaf(hv.x, w0.x, ar[q]); ar[q] = fmaf(hv.y, w0.y, ar[q]);
            az[q] = fmaf(hv.x, w1.x, az[q]); az[q] = fmaf(hv.y, w1.y, az[q]);
            an[q] = fmaf(hv.x, w2.x, an[q]); an[q] = fmaf(hv.y, w2.y, an[q]);
        }
    }
}

__global__ __launch_bounds__(THRG) void gru_step_w(
    const float* __restrict__ x, int xs,             // [BB, *] rows at stride xs
    const float* __restrict__ h,                     // [BB, HH] or nullptr (zeros)
    const float* __restrict__ W_ih, const float* __restrict__ W_hh,
    const float* __restrict__ b_ih, const float* __restrict__ b_hh,
    float* __restrict__ hnew,                        // [BB, HH]
    float* __restrict__ h2, int h2s)                 // optional extra write (h_seq)
{
    __shared__ SmemW sm;
    const int tid = threadIdx.x;
    const int j0 = blockIdx.x * 4, b0 = blockIdx.y * 64;
    const int jj = tid >> 5, bi = tid & 31;
    const int j = j0 + jj;

    // ---- W slice -> LDS: 3 gates x 4 rows x 144 quads = 1728 float4s,
    // 14 guarded quads/thread, pipelined 7+7. k4<16 -> W_ih else W_hh.
    #pragma unroll
    for (int half = 0; half < 2; ++half) {
        float4 tmp[7];
        #pragma unroll
        for (int u = 0; u < 7; ++u) {
            const int i4 = (half * 7 + u) * THRG + tid;
            if (i4 < 1728) {
                const int gg = i4 / 576, rem = i4 - gg * 576;
                const int r = rem / 144, k4 = rem - r * 144;
                const float* src = (k4 < 16)
                    ? &W_ih[(gg * HH + j0 + r) * DD + k4 * 4]
                    : &W_hh[(gg * HH + j0 + r) * HH + (k4 - 16) * 4];
                tmp[u] = *(const float4*)src;
            }
        }
        #pragma unroll
        for (int u = 0; u < 7; ++u) {
            const int i4 = (half * 7 + u) * THRG + tid;
            if (i4 < 1728) {
                const int gg = i4 / 576, rem = i4 - gg * 576;
                const int r = rem / 144, k4 = rem - r * 144;
                *(float4*)&sm.w[gg][r][k4 * 4] = tmp[u];
            }
        }
    }
    const float br  = b_ih[j] + b_hh[j];
    const float bz  = b_ih[HH + j] + b_hh[HH + j];
    const float bin = b_ih[2 * HH + j];
    const float bhn = b_hh[2 * HH + j];

    float ar[2] = {0,0}, az[2] = {0,0}, ain[2] = {0,0}, ahn[2] = {0,0};
    float2 pre[8];

    // ---- x part: K 0..63 (weight cols 0..63) ----
    stage_issue(pre, x, xs, 0, b0, tid);
    stage_commit(sm.hbuf, pre, tid);
    __syncthreads();                                  // covers W load + chunk 0
    stage_issue(pre, x, xs, 32, b0, tid);
    gru_chunk(sm, jj, bi, 0, ar, az, ain);
    __syncthreads();
    stage_commit(sm.hbuf, pre, tid);
    __syncthreads();
    gru_chunk(sm, jj, bi, 32, ar, az, ain);
    __syncthreads();

    // ---- h part: K 0..511 (weight cols 64..575) ----
    if (h) {
        stage_issue(pre, h, HH, 0, b0, tid);
        stage_commit(sm.hbuf, pre, tid);
        __syncthreads();
        for (int c = 0; c < 16; ++c) {
            if (c < 15) stage_issue(pre, h, HH, 32 * (c + 1), b0, tid);
            gru_chunk(sm, jj, bi, 64 + 32 * c, ar, az, ahn);
            __syncthreads();
            if (c < 15) { stage_commit(sm.hbuf, pre, tid); __syncthreads(); }
        }
    }

    // ---- epilogue: n = tanh(i_n + r*h_n); h' = (1-z)n + z h ----
    #pragma unroll
    for (int q = 0; q < 2; ++q) {
        const int b = b0 + bi + 32 * q;
        const float r = sigmoidf_(ar[q] + br);
        const float z = sigmoidf_(az[q] + bz);
        const float hold = h ? h[b * HH + j] : 0.f;
        const float n = tanhf(ain[q] + bin + r * (ahn[q] + bhn));
        const float hn = (1.f - z) * n + z * hold;
        hnew[b * HH + j] = hn;
        if (h2) h2[b * h2s + j] = hn;
    }
}

// ---------------- fc kernels (round-3/9-verified) ----------------
struct SmemOld { float hs[16][34]; float ws[96][34]; };

__global__ __launch_bounds__(256) void fc1_relu(
    const float* __restrict__ h, const float* __restrict__ wsrc,
    const float* __restrict__ bias, float* __restrict__ out) {
    __shared__ SmemOld sm;
    float (*hs)[34] = sm.hs; float (*ws)[34] = sm.ws;
    const int tid = threadIdx.x;
    const int jj = tid & 31, bb = tid >> 5;
    const int j0 = blockIdx.x * 32, b0 = blockIdx.y * 16;
    float a0 = 0.f, a1 = 0.f;
    for (int kt = 0; kt < HH; kt += 32) {
        { const int r = tid >> 4, c2 = (tid & 15) * 2;
          *(float2*)&hs[r][c2] = *(const float2*)&h[(b0 + r) * HH + kt + c2]; }
        #pragma unroll
        for (int i = 0; i < 2; ++i) {
            const int idx = i * 256 + tid, r = idx >> 4, c2 = (idx & 15) * 2;
            *(float2*)&ws[r][c2] = *(const float2*)&wsrc[(j0 + r) * HH + kt + c2];
        }
        __syncthreads();
        #pragma unroll
        for (int k = 0; k < 32; k += 2) {
            const float2 h0 = *(const float2*)&hs[bb][k];
            const float2 h1 = *(const float2*)&hs[bb + 8][k];
            const float2 w0 = *(const float2*)&ws[jj][k];
            a0 = fmaf(h0.x, w0.x, a0); a0 = fmaf(h0.y, w0.y, a0);
            a1 = fmaf(h1.x, w0.x, a1); a1 = fmaf(h1.y, w0.y, a1);
        }
        __syncthreads();
    }
    const float b = bias[j0 + jj];
    out[(b0 + bb) * HH + j0 + jj]     = fmaxf(a0 + b, 0.f);
    out[(b0 + bb + 8) * HH + j0 + jj] = fmaxf(a1 + b, 0.f);
}

__global__ __launch_bounds__(256) void fc2_out(
    const float* __restrict__ a, const float* __restrict__ wsrc,
    const float* __restrict__ bias, float* __restrict__ s_buf,
    float* __restrict__ s_out, int s_stride) {
    __shared__ SmemOld sm;
    float (*as)[34] = sm.hs; float (*ws)[34] = sm.ws;
    const int tid = threadIdx.x;
    const int d = tid & 63, bb = tid >> 6;
    const int b0 = blockIdx.x * 4;
    float acc = 0.f;
    for (int kt = 0; kt < HH; kt += 32) {
        if (tid < 64) { const int r = tid >> 4, c2 = (tid & 15) * 2;
            *(float2*)&as[r][c2] = *(const float2*)&a[(b0 + r) * HH + kt + c2]; }
        #pragma unroll
        for (int i = 0; i < 4; ++i) {
            const int idx = i * 256 + tid, r = idx >> 4, c2 = (idx & 15) * 2;
            *(float2*)&ws[r][c2] = *(const float2*)&wsrc[r * HH + kt + c2];
        }
        __syncthreads();
        #pragma unroll
        for (int k = 0; k < 32; k += 2) {
            const float2 av = *(const float2*)&as[bb][k];
            const float2 wv = *(const float2*)&ws[d][k];
            acc = fmaf(av.x, wv.x, acc); acc = fmaf(av.y, wv.y, acc);
        }
        __syncthreads();
    }
    const float v = acc + bias[d];
    s_buf[(b0 + bb) * DD + d] = v;
    s_out[(b0 + bb) * s_stride + d] = v;
}

extern "C" void kernel_launch(void* const* d_in, const int* in_sizes, int n_in,
                              void* d_out, int out_size, void* d_ws, size_t ws_size,
                              hipStream_t stream) {
    const float* state_seq = (const float*)d_in[0];  // [256,512,64]
    const float* W_ih  = (const float*)d_in[1];      // [1536,64]
    const float* W_hh  = (const float*)d_in[2];      // [1536,512]
    const float* b_ih  = (const float*)d_in[3];
    const float* b_hh  = (const float*)d_in[4];
    const float* fc1_w = (const float*)d_in[5];      // [512,512]
    const float* fc1_b = (const float*)d_in[6];
    const float* fc2_w = (const float*)d_in[7];      // [64,512]
    const float* fc2_b = (const float*)d_in[8];

    float* out_s = (float*)d_out;                    // [256, 32, 64]
    float* out_h = out_s + BB * FF * DD;             // [256, 32, 512]

    float* hA   = (float*)d_ws;
    float* hB   = hA + BB * HH;
    float* aBuf = hB + BB * HH;
    float* sBuf = aBuf + BB * HH;

    const dim3 gruGrid(HH / 4, BB / 64);             // (128, 4) = 512 wgs, 2/CU
    const dim3 gruBlk(THRG);

    // ---- encoder: 512 per-step launches (launch boundary = h sync) ----
    const float* hcur = nullptr;
    for (int t = 0; t < TT; ++t) {
        float* hout = (t & 1) ? hB : hA;
        float* hout2 = (t == TT - 1) ? out_h : nullptr;   // h_seq[:,0,:]
        gru_step_w<<<gruGrid, gruBlk, 0, stream>>>(state_seq + t * DD, TT * DD, hcur,
                                                   W_ih, W_hh, b_ih, b_hh,
                                                   hout, hout2, FF * HH);
        hcur = hout;
    }

    // ---- decoder: 32 fc_predicts, 31 GRU steps ----
    for (int t = 0; t < FF; ++t) {
        fc1_relu<<<dim3(HH / 32, BB / 16), dim3(256), 0, stream>>>(hcur, fc1_w, fc1_b, aBuf);
        fc2_out<<<dim3(BB / 4), dim3(256), 0, stream>>>(aBuf, fc2_w, fc2_b, sBuf,
                                                        out_s + t * DD, FF * DD);
        if (t < FF - 1) {
            float* hout = (hcur == hA) ? hB : hA;
            gru_step_w<<<gruGrid, gruBlk, 0, stream>>>(sBuf, DD, hcur,
                                                       W_ih, W_hh, b_ih, b_hh,
                                                       hout, out_h + (t + 1) * HH, FF * HH);
            hcur = hout;
        }
    }
}

// Round 17
// 12997.752 us; speedup vs baseline: 3.2294x; 1.2965x over previous
//
#include <hip/hip_runtime.h>
#include <hip/hip_cooperative_groups.h>
#include <math.h>

namespace cg = cooperative_groups;

#define BB 256   // batch
#define TT 512   // encoder seq len
#define DD 64    // state dim
#define HH 512   // hidden dim
#define FF 32    // fc_seq_len (decoder steps)
#define THRG 128 // threads per wg (2 waves); 2 wgs/CU via 36.5 KB LDS

__device__ __forceinline__ float sigmoidf_(float x) { return 1.0f / (1.0f + __expf(-x)); }

// ---------------- shared tile structures (round-16-verified) ----------------
struct __align__(16) SmemW {
    float w[3][4][580];    // 27840 B; gate weights, cols 0..63 = W_ih
    float hbuf[64][34];    // 8704 B; staged x/h tile
};                         // 36544 B -> 2 blocks/CU

// stage 64 rows x 32 cols (row stride rs): 8 float2/thread, PLAIN loads.
__device__ __forceinline__ void stage_issue(float2* pre, const float* __restrict__ src,
                                            int rs, int kc, int b0, int tid) {
    #pragma unroll
    for (int u = 0; u < 8; ++u) {
        const int idx = u * THRG + tid, r = idx >> 4, c2 = (idx & 15) * 2;
        pre[u] = *(const float2*)&src[(b0 + r) * rs + kc + c2];
    }
}
// same, but through-to-L3 coherent loads (sc0 sc1) for cross-wg h data.
__device__ __forceinline__ void stage_issue_sc1(float2* pre, const float* src,
                                                int rs, int kc, int b0, int tid) {
    #pragma unroll
    for (int u = 0; u < 8; ++u) {
        const int idx = u * THRG + tid, r = idx >> 4, c2 = (idx & 15) * 2;
        const float2* ap = (const float2*)&src[(b0 + r) * rs + kc + c2];
        asm volatile("global_load_dwordx2 %0, %1, off sc0 sc1"
                     : "=v"(pre[u]) : "v"(ap));
    }
}
// completion fence for sc1 loads: commits must consume THESE outputs.
__device__ __forceinline__ void wait_vals(float2* pre) {
    asm volatile("s_waitcnt vmcnt(0)"
                 : "+v"(pre[0]), "+v"(pre[1]), "+v"(pre[2]), "+v"(pre[3]),
                   "+v"(pre[4]), "+v"(pre[5]), "+v"(pre[6]), "+v"(pre[7])
                 :: "memory");
}
__device__ __forceinline__ void stage_commit(float (*buf)[34], const float2* pre, int tid) {
    #pragma unroll
    for (int u = 0; u < 8; ++u) {
        const int idx = u * THRG + tid, r = idx >> 4, c2 = (idx & 15) * 2;
        *(float2*)&buf[r][c2] = pre[u];
    }
}

// one 32-K chunk of the 3 gate GEMMs (jj in 0..3, 2 rows/thread)
__device__ __forceinline__ void gru_chunk(const SmemW& g, int jj, int bi, int kb,
                                          float* ar, float* az, float* an) {
    #pragma unroll
    for (int kk = 0; kk < 32; kk += 2) {
        const float2 w0 = *(const float2*)&g.w[0][jj][kb + kk];
        const float2 w1 = *(const float2*)&g.w[1][jj][kb + kk];
        const float2 w2 = *(const float2*)&g.w[2][jj][kb + kk];
        #pragma unroll
        for (int q = 0; q < 2; ++q) {
            const float2 hv = *(const float2*)&g.hbuf[bi + 32 * q][kk];
            ar[q] = fmaf(hv.x, w0.x, ar[q]); ar[q] = fmaf(hv.y, w0.y, ar[q]);
            az[q] = fmaf(hv.x, w1.x, az[q]); az[q] = fmaf(hv.y, w1.y, az[q]);
            an[q] = fmaf(hv.x, w2.x, an[q]); an[q] = fmaf(hv.y, w2.y, an[q]);
        }
    }
}

// W slice -> LDS (r16-verified): 1728 float4s, pipelined 7+7 guarded.
__device__ __forceinline__ void load_w(SmemW& sm, const float* __restrict__ W_ih,
                                       const float* __restrict__ W_hh, int j0, int tid) {
    #pragma unroll
    for (int half = 0; half < 2; ++half) {
        float4 tmp[7];
        #pragma unroll
        for (int u = 0; u < 7; ++u) {
            const int i4 = (half * 7 + u) * THRG + tid;
            if (i4 < 1728) {
                const int gg = i4 / 576, rem = i4 - gg * 576;
                const int r = rem / 144, k4 = rem - r * 144;
                const float* src = (k4 < 16)
                    ? &W_ih[(gg * HH + j0 + r) * DD + k4 * 4]
                    : &W_hh[(gg * HH + j0 + r) * HH + (k4 - 16) * 4];
                tmp[u] = *(const float4*)src;
            }
        }
        #pragma unroll
        for (int u = 0; u < 7; ++u) {
            const int i4 = (half * 7 + u) * THRG + tid;
            if (i4 < 1728) {
                const int gg = i4 / 576, rem = i4 - gg * 576;
                const int r = rem / 144, k4 = rem - r * 144;
                *(float4*)&sm.w[gg][r][k4 * 4] = tmp[u];
            }
        }
    }
}

// ---------------- persistent encoder: 512 GRU steps, 1 kernel ----------------
// grid 512: w = blockIdx.x; jt = w>>2 (0..127, 4 j-cols), g = w&3 (64 rows).
// h exchange through L3 (sc0 sc1 loads/stores, no L2 flushes); group barrier =
// one monotone atomic counter per group (lane-0 poll; ops r13-proven).
__global__ void __launch_bounds__(THRG) gru_encoder_pers(
    const float* __restrict__ state_seq,
    const float* __restrict__ W_ih, const float* __restrict__ W_hh,
    const float* __restrict__ b_ih, const float* __restrict__ b_hh,
    float* __restrict__ hA, float* __restrict__ hB,
    float* __restrict__ out_h, int* __restrict__ cnt)
{
    __shared__ SmemW sm;
    const int tid = threadIdx.x;
    const int w = blockIdx.x;
    const int jt = w >> 2, g = w & 3;
    const int j0 = jt * 4, b0 = g * 64;
    const int jj = tid >> 5, bi = tid & 31;
    const int j = j0 + jj;
    int* cnt_g = cnt + g * 16;
    const int cstar = j0 >> 5;            // h-chunk containing col j
    const int jcol = (j0 & 31) + jj;      // col j within that chunk

    if (jt == 0 && tid == 0) *cnt_g = 0;  // zero own group's counter
    cg::this_grid().sync();               // ONE grid sync (round-8-proven)

    load_w(sm, W_ih, W_hh, j0, tid);
    const float br  = b_ih[j] + b_hh[j];
    const float bz  = b_ih[HH + j] + b_hh[HH + j];
    const float bin = b_ih[2 * HH + j];
    const float bhn = b_hh[2 * HH + j];

    for (int t = 0; t < TT; ++t) {
        float* hnew = (t & 1) ? hB : hA;
        const float* hprev = (t == 0) ? nullptr : ((t & 1) ? hA : hB);
        const float* x = state_seq + t * DD;

        float ar[2] = {0,0}, az[2] = {0,0}, ain[2] = {0,0}, ahn[2] = {0,0};
        float hold[2] = {0.f, 0.f};
        float2 pre[8];

        // ---- x part (plain loads; state_seq immutable) ----
        stage_issue(pre, x, TT * DD, 0, b0, tid);
        stage_commit(sm.hbuf, pre, tid);
        __syncthreads();                          // covers W load on t==0 too
        stage_issue(pre, x, TT * DD, 32, b0, tid);
        gru_chunk(sm, jj, bi, 0, ar, az, ain);
        __syncthreads();
        stage_commit(sm.hbuf, pre, tid);
        __syncthreads();
        gru_chunk(sm, jj, bi, 32, ar, az, ain);
        __syncthreads();

        // ---- wait: all group wgs finished step t-1 (h(t-1) reads + h(t) writes)
        if (t > 0) {
            if (tid == 0) { while (atomicAdd(cnt_g, 0) < THRG / THRG * 128 * t) {} }
            __syncthreads();
        }

        // ---- h part (sc1 coherent loads) ----
        if (hprev) {
            stage_issue_sc1(pre, hprev, HH, 0, b0, tid);
            wait_vals(pre);
            stage_commit(sm.hbuf, pre, tid);
            __syncthreads();
            for (int c = 0; c < 16; ++c) {
                if (c < 15) stage_issue_sc1(pre, hprev, HH, 32 * (c + 1), b0, tid);
                if (c == cstar) {                 // grab h(t-1)[b][j] from LDS
                    hold[0] = sm.hbuf[bi][jcol];
                    hold[1] = sm.hbuf[bi + 32][jcol];
                }
                gru_chunk(sm, jj, bi, 64 + 32 * c, ar, az, ahn);
                __syncthreads();
                if (c < 15) {
                    wait_vals(pre);
                    stage_commit(sm.hbuf, pre, tid);
                    __syncthreads();
                }
            }
        }

        // ---- epilogue: sc1 stores of h(t+1) slice ----
        #pragma unroll
        for (int q = 0; q < 2; ++q) {
            const int b = b0 + bi + 32 * q;
            const float r = sigmoidf_(ar[q] + br);
            const float z = sigmoidf_(az[q] + bz);
            const float n = tanhf(ain[q] + bin + r * (ahn[q] + bhn));
            const float hn = (1.f - z) * n + z * hold[q];
            float* hp = &hnew[b * HH + j];
            asm volatile("global_store_dword %0, %1, off sc0 sc1"
                         :: "v"(hp), "v"(hn) : "memory");
            if (t == TT - 1) out_h[b * (FF * HH) + j] = hn;   // h_seq[:,0,:]
        }

        // ---- arrive: own stores complete -> all threads done -> flag ----
        asm volatile("s_waitcnt vmcnt(0)" ::: "memory");
        __syncthreads();
        if (tid == 0) atomicAdd(cnt_g, 1);
    }
}

// ---------------- per-step GRU kernel (round-16-verified fallback/decoder) ----
__global__ __launch_bounds__(THRG) void gru_step_w(
    const float* __restrict__ x, int xs, const float* __restrict__ h,
    const float* __restrict__ W_ih, const float* __restrict__ W_hh,
    const float* __restrict__ b_ih, const float* __restrict__ b_hh,
    float* __restrict__ hnew, float* __restrict__ h2, int h2s)
{
    __shared__ SmemW sm;
    const int tid = threadIdx.x;
    const int j0 = blockIdx.x * 4, b0 = blockIdx.y * 64;
    const int jj = tid >> 5, bi = tid & 31;
    const int j = j0 + jj;

    load_w(sm, W_ih, W_hh, j0, tid);
    const float br  = b_ih[j] + b_hh[j];
    const float bz  = b_ih[HH + j] + b_hh[HH + j];
    const float bin = b_ih[2 * HH + j];
    const float bhn = b_hh[2 * HH + j];

    float ar[2] = {0,0}, az[2] = {0,0}, ain[2] = {0,0}, ahn[2] = {0,0};
    float2 pre[8];

    stage_issue(pre, x, xs, 0, b0, tid);
    stage_commit(sm.hbuf, pre, tid);
    __syncthreads();
    stage_issue(pre, x, xs, 32, b0, tid);
    gru_chunk(sm, jj, bi, 0, ar, az, ain);
    __syncthreads();
    stage_commit(sm.hbuf, pre, tid);
    __syncthreads();
    gru_chunk(sm, jj, bi, 32, ar, az, ain);
    __syncthreads();

    if (h) {
        stage_issue(pre, h, HH, 0, b0, tid);
        stage_commit(sm.hbuf, pre, tid);
        __syncthreads();
        for (int c = 0; c < 16; ++c) {
            if (c < 15) stage_issue(pre, h, HH, 32 * (c + 1), b0, tid);
            gru_chunk(sm, jj, bi, 64 + 32 * c, ar, az, ahn);
            __syncthreads();
            if (c < 15) { stage_commit(sm.hbuf, pre, tid); __syncthreads(); }
        }
    }

    #pragma unroll
    for (int q = 0; q < 2; ++q) {
        const int b = b0 + bi + 32 * q;
        const float r = sigmoidf_(ar[q] + br);
        const float z = sigmoidf_(az[q] + bz);
        const float hold = h ? h[b * HH + j] : 0.f;
        const float n = tanhf(ain[q] + bin + r * (ahn[q] + bhn));
        const float hn = (1.f - z) * n + z * hold;
        hnew[b * HH + j] = hn;
        if (h2) h2[b * h2s + j] = hn;
    }
}

// ---------------- fc kernels (round-3/9/16-verified) ----------------
struct SmemOld { float hs[16][34]; float ws[96][34]; };

__global__ __launch_bounds__(256) void fc1_relu(
    const float* __restrict__ h, const float* __restrict__ wsrc,
    const float* __restrict__ bias, float* __restrict__ out) {
    __shared__ SmemOld sm;
    float (*hs)[34] = sm.hs; float (*ws)[34] = sm.ws;
    const int tid = threadIdx.x;
    const int jj = tid & 31, bb = tid >> 5;
    const int j0 = blockIdx.x * 32, b0 = blockIdx.y * 16;
    float a0 = 0.f, a1 = 0.f;
    for (int kt = 0; kt < HH; kt += 32) {
        { const int r = tid >> 4, c2 = (tid & 15) * 2;
          *(float2*)&hs[r][c2] = *(const float2*)&h[(b0 + r) * HH + kt + c2]; }
        #pragma unroll
        for (int i = 0; i < 2; ++i) {
            const int idx = i * 256 + tid, r = idx >> 4, c2 = (idx & 15) * 2;
            *(float2*)&ws[r][c2] = *(const float2*)&wsrc[(j0 + r) * HH + kt + c2];
        }
        __syncthreads();
        #pragma unroll
        for (int k = 0; k < 32; k += 2) {
            const float2 h0 = *(const float2*)&hs[bb][k];
            const float2 h1 = *(const float2*)&hs[bb + 8][k];
            const float2 w0 = *(const float2*)&ws[jj][k];
            a0 = fmaf(h0.x, w0.x, a0); a0 = fmaf(h0.y, w0.y, a0);
            a1 = fmaf(h1.x, w0.x, a1); a1 = fmaf(h1.y, w0.y, a1);
        }
        __syncthreads();
    }
    const float b = bias[j0 + jj];
    out[(b0 + bb) * HH + j0 + jj]     = fmaxf(a0 + b, 0.f);
    out[(b0 + bb + 8) * HH + j0 + jj] = fmaxf(a1 + b, 0.f);
}

__global__ __launch_bounds__(256) void fc2_out(
    const float* __restrict__ a, const float* __restrict__ wsrc,
    const float* __restrict__ bias, float* __restrict__ s_buf,
    float* __restrict__ s_out, int s_stride) {
    __shared__ SmemOld sm;
    float (*as)[34] = sm.hs; float (*ws)[34] = sm.ws;
    const int tid = threadIdx.x;
    const int d = tid & 63, bb = tid >> 6;
    const int b0 = blockIdx.x * 4;
    float acc = 0.f;
    for (int kt = 0; kt < HH; kt += 32) {
        if (tid < 64) { const int r = tid >> 4, c2 = (tid & 15) * 2;
            *(float2*)&as[r][c2] = *(const float2*)&a[(b0 + r) * HH + kt + c2]; }
        #pragma unroll
        for (int i = 0; i < 4; ++i) {
            const int idx = i * 256 + tid, r = idx >> 4, c2 = (idx & 15) * 2;
            *(float2*)&ws[r][c2] = *(const float2*)&wsrc[r * HH + kt + c2];
        }
        __syncthreads();
        #pragma unroll
        for (int k = 0; k < 32; k += 2) {
            const float2 av = *(const float2*)&as[bb][k];
            const float2 wv = *(const float2*)&ws[d][k];
            acc = fmaf(av.x, wv.x, acc); acc = fmaf(av.y, wv.y, acc);
        }
        __syncthreads();
    }
    const float v = acc + bias[d];
    s_buf[(b0 + bb) * DD + d] = v;
    s_out[(b0 + bb) * s_stride + d] = v;
}

extern "C" void kernel_launch(void* const* d_in, const int* in_sizes, int n_in,
                              void* d_out, int out_size, void* d_ws, size_t ws_size,
                              hipStream_t stream) {
    const float* state_seq = (const float*)d_in[0];  // [256,512,64]
    const float* W_ih  = (const float*)d_in[1];      // [1536,64]
    const float* W_hh  = (const float*)d_in[2];      // [1536,512]
    const float* b_ih  = (const float*)d_in[3];
    const float* b_hh  = (const float*)d_in[4];
    const float* fc1_w = (const float*)d_in[5];      // [512,512]
    const float* fc1_b = (const float*)d_in[6];
    const float* fc2_w = (const float*)d_in[7];      // [64,512]
    const float* fc2_b = (const float*)d_in[8];

    float* out_s = (float*)d_out;                    // [256, 32, 64]
    float* out_h = out_s + BB * FF * DD;             // [256, 32, 512]

    float* hA   = (float*)d_ws;
    float* hB   = hA + BB * HH;
    float* aBuf = hB + BB * HH;
    float* sBuf = aBuf + BB * HH;
    int*   cnt  = (int*)(sBuf + BB * DD);            // 4 counters x 64 B
    const size_t need = (size_t)(3 * BB * HH + BB * DD) * 4 + 4 * 16 * 4;

    const dim3 gruGrid(HH / 4, BB / 64);             // (128, 4)
    const dim3 gruBlk(THRG);

    // ---- encoder: ONE persistent cooperative kernel (L3-coherent h exchange)
    bool enc_done = false;
    if (ws_size >= need) {
        void* args[] = { (void*)&state_seq, (void*)&W_ih, (void*)&W_hh,
                         (void*)&b_ih, (void*)&b_hh, (void*)&hA, (void*)&hB,
                         (void*)&out_h, (void*)&cnt };
        hipError_t e = hipLaunchCooperativeKernel((const void*)gru_encoder_pers,
                                                  dim3(512), gruBlk, args, 0, stream);
        enc_done = (e == hipSuccess);
        if (!enc_done) (void)hipGetLastError();
    }

    const float* hcur;
    if (enc_done) {
        hcur = hB;                                   // t=511 wrote hB
    } else {
        // fallback: round-16 verified per-step encoder
        const float* hprev = nullptr;
        for (int t = 0; t < TT; ++t) {
            float* hout = (t & 1) ? hB : hA;
            float* hout2 = (t == TT - 1) ? out_h : nullptr;
            gru_step_w<<<gruGrid, gruBlk, 0, stream>>>(state_seq + t * DD, TT * DD,
                                                       hprev, W_ih, W_hh, b_ih, b_hh,
                                                       hout, hout2, FF * HH);
            hprev = hout;
        }
        hcur = hprev;
    }

    // ---- decoder: 32 fc_predicts, 31 GRU steps (round-16-verified) ----
    for (int t = 0; t < FF; ++t) {
        fc1_relu<<<dim3(HH / 32, BB / 16), dim3(256), 0, stream>>>(hcur, fc1_w, fc1_b, aBuf);
        fc2_out<<<dim3(BB / 4), dim3(256), 0, stream>>>(aBuf, fc2_w, fc2_b, sBuf,
                                                        out_s + t * DD, FF * DD);
        if (t < FF - 1) {
            float* hout = (hcur == hA) ? hB : hA;
            gru_step_w<<<gruGrid, gruBlk, 0, stream>>>(sBuf, DD, hcur,
                                                       W_ih, W_hh, b_ih, b_hh,
                                                       hout, out_h + (t + 1) * HH, FF * HH);
            hcur = hout;
        }
    }
}

// Round 18
// 11293.201 us; speedup vs baseline: 3.7168x; 1.1509x over previous
//
#include <hip/hip_runtime.h>
#include <hip/hip_cooperative_groups.h>
#include <math.h>

namespace cg = cooperative_groups;

#define BB 256   // batch
#define TT 512   // encoder seq len
#define DD 64    // state dim
#define HH 512   // hidden dim
#define FF 32    // fc_seq_len (decoder steps)
#define THRG 128 // threads per wg (2 waves); 2 wgs/CU via 36.5 KB LDS
#define SLOTP 16 // flag slot padding (ints) -> 64 B/slot

__device__ __forceinline__ float sigmoidf_(float x) { return 1.0f / (1.0f + __expf(-x)); }

// ---------------- shared tile structures (round-16/17-verified) ----------------
struct __align__(16) SmemW {
    float w[3][4][580];    // 27840 B; gate weights, cols 0..63 = W_ih
    float hbuf[64][34];    // 8704 B; staged x/h tile
};                         // 36544 B -> 2 blocks/CU

// stage 64 rows x 32 cols (row stride rs): 8 float2/thread, PLAIN loads.
__device__ __forceinline__ void stage_issue(float2* pre, const float* __restrict__ src,
                                            int rs, int kc, int b0, int tid) {
    #pragma unroll
    for (int u = 0; u < 8; ++u) {
        const int idx = u * THRG + tid, r = idx >> 4, c2 = (idx & 15) * 2;
        pre[u] = *(const float2*)&src[(b0 + r) * rs + kc + c2];
    }
}
// same, but through-to-L3 coherent loads (sc0 sc1) for cross-wg h data.
__device__ __forceinline__ void stage_issue_sc1(float2* pre, const float* src,
                                                int rs, int kc, int b0, int tid) {
    #pragma unroll
    for (int u = 0; u < 8; ++u) {
        const int idx = u * THRG + tid, r = idx >> 4, c2 = (idx & 15) * 2;
        const float2* ap = (const float2*)&src[(b0 + r) * rs + kc + c2];
        asm volatile("global_load_dwordx2 %0, %1, off sc0 sc1"
                     : "=v"(pre[u]) : "v"(ap));
    }
}
// completion fence for sc1 loads: commits must consume THESE outputs.
__device__ __forceinline__ void wait_vals(float2* pre) {
    asm volatile("s_waitcnt vmcnt(0)"
                 : "+v"(pre[0]), "+v"(pre[1]), "+v"(pre[2]), "+v"(pre[3]),
                   "+v"(pre[4]), "+v"(pre[5]), "+v"(pre[6]), "+v"(pre[7])
                 :: "memory");
}
__device__ __forceinline__ void stage_commit(float (*buf)[34], const float2* pre, int tid) {
    #pragma unroll
    for (int u = 0; u < 8; ++u) {
        const int idx = u * THRG + tid, r = idx >> 4, c2 = (idx & 15) * 2;
        *(float2*)&buf[r][c2] = pre[u];
    }
}

// sc1 flag ops (L3-coherent, no RMW, no fences)
__device__ __forceinline__ int load_flag_sc1(const int* p) {
    int v;
    asm volatile("global_load_dword %0, %1, off sc0 sc1\n\ts_waitcnt vmcnt(0)"
                 : "=v"(v) : "v"(p) : "memory");
    return v;
}
__device__ __forceinline__ void store_flag_sc1(int* p, int v) {
    asm volatile("global_store_dword %0, %1, off sc0 sc1" :: "v"(p), "v"(v) : "memory");
}

// one 32-K chunk of the 3 gate GEMMs (jj in 0..3, 2 rows/thread)
__device__ __forceinline__ void gru_chunk(const SmemW& g, int jj, int bi, int kb,
                                          float* ar, float* az, float* an) {
    #pragma unroll
    for (int kk = 0; kk < 32; kk += 2) {
        const float2 w0 = *(const float2*)&g.w[0][jj][kb + kk];
        const float2 w1 = *(const float2*)&g.w[1][jj][kb + kk];
        const float2 w2 = *(const float2*)&g.w[2][jj][kb + kk];
        #pragma unroll
        for (int q = 0; q < 2; ++q) {
            const float2 hv = *(const float2*)&g.hbuf[bi + 32 * q][kk];
            ar[q] = fmaf(hv.x, w0.x, ar[q]); ar[q] = fmaf(hv.y, w0.y, ar[q]);
            az[q] = fmaf(hv.x, w1.x, az[q]); az[q] = fmaf(hv.y, w1.y, az[q]);
            an[q] = fmaf(hv.x, w2.x, an[q]); an[q] = fmaf(hv.y, w2.y, an[q]);
        }
    }
}

// W slice -> LDS (r16-verified): 1728 float4s, pipelined 7+7 guarded.
__device__ __forceinline__ void load_w(SmemW& sm, const float* __restrict__ W_ih,
                                       const float* __restrict__ W_hh, int j0, int tid) {
    #pragma unroll
    for (int half = 0; half < 2; ++half) {
        float4 tmp[7];
        #pragma unroll
        for (int u = 0; u < 7; ++u) {
            const int i4 = (half * 7 + u) * THRG + tid;
            if (i4 < 1728) {
                const int gg = i4 / 576, rem = i4 - gg * 576;
                const int r = rem / 144, k4 = rem - r * 144;
                const float* src = (k4 < 16)
                    ? &W_ih[(gg * HH + j0 + r) * DD + k4 * 4]
                    : &W_hh[(gg * HH + j0 + r) * HH + (k4 - 16) * 4];
                tmp[u] = *(const float4*)src;
            }
        }
        #pragma unroll
        for (int u = 0; u < 7; ++u) {
            const int i4 = (half * 7 + u) * THRG + tid;
            if (i4 < 1728) {
                const int gg = i4 / 576, rem = i4 - gg * 576;
                const int r = rem / 144, k4 = rem - r * 144;
                *(float4*)&sm.w[gg][r][k4 * 4] = tmp[u];
            }
        }
    }
}

// ---------------- persistent encoder: 512 GRU steps, 1 kernel ----------------
// grid 512: w = blockIdx.x; jt = w>>2 (0..127, 4 j-cols), g = w&3 (64 rows).
// h exchange through L3 (sc0 sc1); group barrier = per-wg FLAG slots (64 B
// apart): arrive = vmcnt(0) + sync + lane-0 sc1 store of t+1; wait = each of
// 128 lanes polls one slot with sc1 loads (parallel reads, no RMW serialization
// -- round 17's single atomicAdd counter was the bottleneck).
__global__ void __launch_bounds__(THRG) gru_encoder_pers(
    const float* __restrict__ state_seq,
    const float* __restrict__ W_ih, const float* __restrict__ W_hh,
    const float* __restrict__ b_ih, const float* __restrict__ b_hh,
    float* __restrict__ hA, float* __restrict__ hB,
    float* __restrict__ out_h, int* __restrict__ bar)
{
    __shared__ SmemW sm;
    const int tid = threadIdx.x;
    const int w = blockIdx.x;
    const int jt = w >> 2, g = w & 3;
    const int j0 = jt * 4, b0 = g * 64;
    const int jj = tid >> 5, bi = tid & 31;
    const int j = j0 + jj;
    int* slot_own  = bar + (g * 128 + jt) * SLOTP;
    int* slot_poll = bar + (g * 128 + tid) * SLOTP;   // lane tid polls wg (g,tid)
    const int cstar = j0 >> 5;            // h-chunk containing col j
    const int jcol = (j0 & 31) + jj;      // col j within that chunk

    if (tid == 0) *slot_own = 0;          // zero own slot
    cg::this_grid().sync();               // ONE grid sync (round-8-proven)

    load_w(sm, W_ih, W_hh, j0, tid);
    const float br  = b_ih[j] + b_hh[j];
    const float bz  = b_ih[HH + j] + b_hh[HH + j];
    const float bin = b_ih[2 * HH + j];
    const float bhn = b_hh[2 * HH + j];

    for (int t = 0; t < TT; ++t) {
        float* hnew = (t & 1) ? hB : hA;
        const float* hprev = (t == 0) ? nullptr : ((t & 1) ? hA : hB);
        const float* x = state_seq + t * DD;

        float ar[2] = {0,0}, az[2] = {0,0}, ain[2] = {0,0}, ahn[2] = {0,0};
        float hold[2] = {0.f, 0.f};
        float2 pre[8];

        // ---- x part (plain loads; state_seq immutable) ----
        stage_issue(pre, x, TT * DD, 0, b0, tid);
        stage_commit(sm.hbuf, pre, tid);
        __syncthreads();                          // covers W load on t==0 too
        stage_issue(pre, x, TT * DD, 32, b0, tid);
        gru_chunk(sm, jj, bi, 0, ar, az, ain);
        __syncthreads();
        stage_commit(sm.hbuf, pre, tid);
        __syncthreads();
        gru_chunk(sm, jj, bi, 32, ar, az, ain);
        __syncthreads();

        // ---- wait: all group wgs flagged completion of step t-1 ----
        if (t > 0) {
            while (load_flag_sc1(slot_poll) < t) { }
            __syncthreads();
        }

        // ---- h part (sc1 coherent loads) ----
        if (hprev) {
            stage_issue_sc1(pre, hprev, HH, 0, b0, tid);
            wait_vals(pre);
            stage_commit(sm.hbuf, pre, tid);
            __syncthreads();
            for (int c = 0; c < 16; ++c) {
                if (c < 15) stage_issue_sc1(pre, hprev, HH, 32 * (c + 1), b0, tid);
                if (c == cstar) {                 // grab h(t-1)[b][j] from LDS
                    hold[0] = sm.hbuf[bi][jcol];
                    hold[1] = sm.hbuf[bi + 32][jcol];
                }
                gru_chunk(sm, jj, bi, 64 + 32 * c, ar, az, ahn);
                __syncthreads();
                if (c < 15) {
                    wait_vals(pre);
                    stage_commit(sm.hbuf, pre, tid);
                    __syncthreads();
                }
            }
        }

        // ---- epilogue: sc1 stores of h(t) slice ----
        #pragma unroll
        for (int q = 0; q < 2; ++q) {
            const int b = b0 + bi + 32 * q;
            const float r = sigmoidf_(ar[q] + br);
            const float z = sigmoidf_(az[q] + bz);
            const float n = tanhf(ain[q] + bin + r * (ahn[q] + bhn));
            const float hn = (1.f - z) * n + z * hold[q];
            float* hp = &hnew[b * HH + j];
            asm volatile("global_store_dword %0, %1, off sc0 sc1"
                         :: "v"(hp), "v"(hn) : "memory");
            if (t == TT - 1) out_h[b * (FF * HH) + j] = hn;   // h_seq[:,0,:]
        }

        // ---- arrive: own stores complete -> all threads done -> flag t+1 ----
        asm volatile("s_waitcnt vmcnt(0)" ::: "memory");
        __syncthreads();
        if (tid == 0) store_flag_sc1(slot_own, t + 1);
    }
}

// ---------------- per-step GRU kernel (round-16-verified fallback/decoder) ----
__global__ __launch_bounds__(THRG) void gru_step_w(
    const float* __restrict__ x, int xs, const float* __restrict__ h,
    const float* __restrict__ W_ih, const float* __restrict__ W_hh,
    const float* __restrict__ b_ih, const float* __restrict__ b_hh,
    float* __restrict__ hnew, float* __restrict__ h2, int h2s)
{
    __shared__ SmemW sm;
    const int tid = threadIdx.x;
    const int j0 = blockIdx.x * 4, b0 = blockIdx.y * 64;
    const int jj = tid >> 5, bi = tid & 31;
    const int j = j0 + jj;

    load_w(sm, W_ih, W_hh, j0, tid);
    const float br  = b_ih[j] + b_hh[j];
    const float bz  = b_ih[HH + j] + b_hh[HH + j];
    const float bin = b_ih[2 * HH + j];
    const float bhn = b_hh[2 * HH + j];

    float ar[2] = {0,0}, az[2] = {0,0}, ain[2] = {0,0}, ahn[2] = {0,0};
    float2 pre[8];

    stage_issue(pre, x, xs, 0, b0, tid);
    stage_commit(sm.hbuf, pre, tid);
    __syncthreads();
    stage_issue(pre, x, xs, 32, b0, tid);
    gru_chunk(sm, jj, bi, 0, ar, az, ain);
    __syncthreads();
    stage_commit(sm.hbuf, pre, tid);
    __syncthreads();
    gru_chunk(sm, jj, bi, 32, ar, az, ain);
    __syncthreads();

    if (h) {
        stage_issue(pre, h, HH, 0, b0, tid);
        stage_commit(sm.hbuf, pre, tid);
        __syncthreads();
        for (int c = 0; c < 16; ++c) {
            if (c < 15) stage_issue(pre, h, HH, 32 * (c + 1), b0, tid);
            gru_chunk(sm, jj, bi, 64 + 32 * c, ar, az, ahn);
            __syncthreads();
            if (c < 15) { stage_commit(sm.hbuf, pre, tid); __syncthreads(); }
        }
    }

    #pragma unroll
    for (int q = 0; q < 2; ++q) {
        const int b = b0 + bi + 32 * q;
        const float r = sigmoidf_(ar[q] + br);
        const float z = sigmoidf_(az[q] + bz);
        const float hold = h ? h[b * HH + j] : 0.f;
        const float n = tanhf(ain[q] + bin + r * (ahn[q] + bhn));
        const float hn = (1.f - z) * n + z * hold;
        hnew[b * HH + j] = hn;
        if (h2) h2[b * h2s + j] = hn;
    }
}

// ---------------- fc kernels (round-3/9/16-verified) ----------------
struct SmemOld { float hs[16][34]; float ws[96][34]; };

__global__ __launch_bounds__(256) void fc1_relu(
    const float* __restrict__ h, const float* __restrict__ wsrc,
    const float* __restrict__ bias, float* __restrict__ out) {
    __shared__ SmemOld sm;
    float (*hs)[34] = sm.hs; float (*ws)[34] = sm.ws;
    const int tid = threadIdx.x;
    const int jj = tid & 31, bb = tid >> 5;
    const int j0 = blockIdx.x * 32, b0 = blockIdx.y * 16;
    float a0 = 0.f, a1 = 0.f;
    for (int kt = 0; kt < HH; kt += 32) {
        { const int r = tid >> 4, c2 = (tid & 15) * 2;
          *(float2*)&hs[r][c2] = *(const float2*)&h[(b0 + r) * HH + kt + c2]; }
        #pragma unroll
        for (int i = 0; i < 2; ++i) {
            const int idx = i * 256 + tid, r = idx >> 4, c2 = (idx & 15) * 2;
            *(float2*)&ws[r][c2] = *(const float2*)&wsrc[(j0 + r) * HH + kt + c2];
        }
        __syncthreads();
        #pragma unroll
        for (int k = 0; k < 32; k += 2) {
            const float2 h0 = *(const float2*)&hs[bb][k];
            const float2 h1 = *(const float2*)&hs[bb + 8][k];
            const float2 w0 = *(const float2*)&ws[jj][k];
            a0 = fmaf(h0.x, w0.x, a0); a0 = fmaf(h0.y, w0.y, a0);
            a1 = fmaf(h1.x, w0.x, a1); a1 = fmaf(h1.y, w0.y, a1);
        }
        __syncthreads();
    }
    const float b = bias[j0 + jj];
    out[(b0 + bb) * HH + j0 + jj]     = fmaxf(a0 + b, 0.f);
    out[(b0 + bb + 8) * HH + j0 + jj] = fmaxf(a1 + b, 0.f);
}

__global__ __launch_bounds__(256) void fc2_out(
    const float* __restrict__ a, const float* __restrict__ wsrc,
    const float* __restrict__ bias, float* __restrict__ s_buf,
    float* __restrict__ s_out, int s_stride) {
    __shared__ SmemOld sm;
    float (*as)[34] = sm.hs; float (*ws)[34] = sm.ws;
    const int tid = threadIdx.x;
    const int d = tid & 63, bb = tid >> 6;
    const int b0 = blockIdx.x * 4;
    float acc = 0.f;
    for (int kt = 0; kt < HH; kt += 32) {
        if (tid < 64) { const int r = tid >> 4, c2 = (tid & 15) * 2;
            *(float2*)&as[r][c2] = *(const float2*)&a[(b0 + r) * HH + kt + c2]; }
        #pragma unroll
        for (int i = 0; i < 4; ++i) {
            const int idx = i * 256 + tid, r = idx >> 4, c2 = (idx & 15) * 2;
            *(float2*)&ws[r][c2] = *(const float2*)&wsrc[r * HH + kt + c2];
        }
        __syncthreads();
        #pragma unroll
        for (int k = 0; k < 32; k += 2) {
            const float2 av = *(const float2*)&as[bb][k];
            const float2 wv = *(const float2*)&ws[d][k];
            acc = fmaf(av.x, wv.x, acc); acc = fmaf(av.y, wv.y, acc);
        }
        __syncthreads();
    }
    const float v = acc + bias[d];
    s_buf[(b0 + bb) * DD + d] = v;
    s_out[(b0 + bb) * s_stride + d] = v;
}

extern "C" void kernel_launch(void* const* d_in, const int* in_sizes, int n_in,
                              void* d_out, int out_size, void* d_ws, size_t ws_size,
                              hipStream_t stream) {
    const float* state_seq = (const float*)d_in[0];  // [256,512,64]
    const float* W_ih  = (const float*)d_in[1];      // [1536,64]
    const float* W_hh  = (const float*)d_in[2];      // [1536,512]
    const float* b_ih  = (const float*)d_in[3];
    const float* b_hh  = (const float*)d_in[4];
    const float* fc1_w = (const float*)d_in[5];      // [512,512]
    const float* fc1_b = (const float*)d_in[6];
    const float* fc2_w = (const float*)d_in[7];      // [64,512]
    const float* fc2_b = (const float*)d_in[8];

    float* out_s = (float*)d_out;                    // [256, 32, 64]
    float* out_h = out_s + BB * FF * DD;             // [256, 32, 512]

    float* hA   = (float*)d_ws;
    float* hB   = hA + BB * HH;
    float* aBuf = hB + BB * HH;
    float* sBuf = aBuf + BB * HH;
    int*   bar  = (int*)(sBuf + BB * DD);            // 512 slots x 64 B
    const size_t need = (size_t)(3 * BB * HH + BB * DD) * 4 + (size_t)512 * SLOTP * 4;

    const dim3 gruGrid(HH / 4, BB / 64);             // (128, 4)
    const dim3 gruBlk(THRG);

    // ---- encoder: ONE persistent cooperative kernel (L3-coherent h exchange)
    bool enc_done = false;
    if (ws_size >= need) {
        void* args[] = { (void*)&state_seq, (void*)&W_ih, (void*)&W_hh,
                         (void*)&b_ih, (void*)&b_hh, (void*)&hA, (void*)&hB,
                         (void*)&out_h, (void*)&bar };
        hipError_t e = hipLaunchCooperativeKernel((const void*)gru_encoder_pers,
                                                  dim3(512), gruBlk, args, 0, stream);
        enc_done = (e == hipSuccess);
        if (!enc_done) (void)hipGetLastError();
    }

    const float* hcur;
    if (enc_done) {
        hcur = hB;                                   // t=511 wrote hB
    } else {
        // fallback: round-16 verified per-step encoder
        const float* hprev = nullptr;
        for (int t = 0; t < TT; ++t) {
            float* hout = (t & 1) ? hB : hA;
            float* hout2 = (t == TT - 1) ? out_h : nullptr;
            gru_step_w<<<gruGrid, gruBlk, 0, stream>>>(state_seq + t * DD, TT * DD,
                                                       hprev, W_ih, W_hh, b_ih, b_hh,
                                                       hout, hout2, FF * HH);
            hprev = hout;
        }
        hcur = hprev;
    }

    // ---- decoder: 32 fc_predicts, 31 GRU steps (round-16-verified) ----
    for (int t = 0; t < FF; ++t) {
        fc1_relu<<<dim3(HH / 32, BB / 16), dim3(256), 0, stream>>>(hcur, fc1_w, fc1_b, aBuf);
        fc2_out<<<dim3(BB / 4), dim3(256), 0, stream>>>(aBuf, fc2_w, fc2_b, sBuf,
                                                        out_s + t * DD, FF * DD);
        if (t < FF - 1) {
            float* hout = (hcur == hA) ? hB : hA;
            gru_step_w<<<gruGrid, gruBlk, 0, stream>>>(sBuf, DD, hcur,
                                                       W_ih, W_hh, b_ih, b_hh,
                                                       hout, out_h + (t + 1) * HH, FF * HH);
            hcur = hout;
        }
    }
}